// Round 11
// baseline (27.954 us; speedup 1.0000x reference)
//
#include <hip/hip_runtime.h>

// Problem constants (B=1)
#define H 8
#define S 4096
#define D 64          // D1 == D2 == 64
#define C 64          // chunk length
#define NC (S / C)    // 64 chunks per head
#define DD (D * D)
#define PITCH 72      // bf16 LDS row pitch (144B, 16B-aligned, 4-bank rotation)

typedef short bf16x8 __attribute__((ext_vector_type(8)));
typedef float f32x4 __attribute__((ext_vector_type(4)));
typedef unsigned uint4v __attribute__((ext_vector_type(4)));

struct alignas(16) F4 { float v[4]; };

__device__ inline unsigned short rne_bf16(float x) {
  unsigned u = __builtin_bit_cast(unsigned, x);
  unsigned r = u + 0x7fffu + ((u >> 16) & 1u);
  return (unsigned short)(r >> 16);
}
__device__ inline float bf16_to_f(unsigned hw) {
  return __builtin_bit_cast(float, hw << 16);
}

// ---------------------------------------------------------------------------
// Kernel 1 (512 thr, 8 waves): per-chunk state via MFMA, bf16 out:
//   wsKV[h][ch][c][a] = bf16( sum_i v[i][c] * k_bar[i][a] )
// ---------------------------------------------------------------------------
__global__ __launch_bounds__(512, 4) void k_chunk_sums(
    const float* __restrict__ k, const float* __restrict__ v,
    const float* __restrict__ coef_k, unsigned short* __restrict__ wsKV) {
  const int ch = blockIdx.x, h = blockIdx.y, t = threadIdx.x;
  __shared__ alignas(16) short kT[C * PITCH];   // k_bar^T [a][i]
  __shared__ alignas(16) short vT[C * PITCH];   // v^T     [c][i]

  const float* kp = k + (size_t)(h * S + ch * C) * D;
  const float* vp = v + (size_t)(h * S + ch * C) * D;
  const float* ck = coef_k + h * S + ch * C;

  // staging: col = t&63; grp = t>>6: grp<4 -> kT (i0=16*grp), else vT
  {
    const int col = t & 63, grp = t >> 6;
    const bool isK = grp < 4;
    const int i0 = (grp & 3) * 16;
    const float* src = isK ? kp : vp;
    short* dstT = isK ? kT : vT;
    unsigned pr[8];
#pragma unroll
    for (int u2 = 0; u2 < 8; ++u2) {
      const int ia = i0 + 2 * u2, ib = ia + 1;
      float x0 = src[ia * D + col];
      float x1 = src[ib * D + col];
      if (isK) { x0 *= ck[ia]; x1 *= ck[ib]; }
      pr[u2] = (unsigned)rne_bf16(x0) | ((unsigned)rne_bf16(x1) << 16);
    }
#pragma unroll
    for (int g = 0; g < 2; ++g) {
      uint4v wv = {pr[4 * g], pr[4 * g + 1], pr[4 * g + 2], pr[4 * g + 3]};
      *reinterpret_cast<uint4v*>(&dstT[col * PITCH + i0 + 8 * g]) = wv;
    }
  }
  __syncthreads();

  // MFMA: wave w -> row-tile m = w>>1 (c), col-tiles n0..n0+1 (a)
  const int lane = t & 63, w = t >> 6;
  const int arow = lane & 15, kg = lane >> 4;
  const int m = w >> 1, n0 = 2 * (w & 1);
  const int abase = (16 * m + arow) * PITCH + 8 * kg;
  bf16x8 a0 = *reinterpret_cast<const bf16x8*>(&vT[abase]);
  bf16x8 a1 = *reinterpret_cast<const bf16x8*>(&vT[abase + 32]);
  unsigned short* dst = wsKV + (size_t)(h * NC + ch) * DD;
#pragma unroll
  for (int nn = 0; nn < 2; ++nn) {
    const int n = n0 + nn;
    const int bb = (16 * n + arow) * PITCH + 8 * kg;
    bf16x8 b0 = *reinterpret_cast<const bf16x8*>(&kT[bb]);
    bf16x8 b1 = *reinterpret_cast<const bf16x8*>(&kT[bb + 32]);
    f32x4 z = {0.f, 0.f, 0.f, 0.f};
    z = __builtin_amdgcn_mfma_f32_16x16x32_bf16(a0, b0, z, 0, 0, 0);
    z = __builtin_amdgcn_mfma_f32_16x16x32_bf16(a1, b1, z, 0, 0, 0);
#pragma unroll
    for (int r = 0; r < 4; ++r)
      dst[(16 * m + 4 * kg + r) * D + 16 * n + arow] = rne_bf16(z[r]);
  }
}

// ---------------------------------------------------------------------------
// Kernel 2 (512 thr, 8 waves): output; S0 computed IN-BLOCK by summing the
// ch prior chunk states (f32 acc over bf16, ascending order == old k_scan).
//   A = tril(q_bar K_bar^T);  O = q_bar*S0 + A*V;  rmsnorm(O).
// ---------------------------------------------------------------------------
__global__ __launch_bounds__(512, 4) void k_chunk_out(
    const float* __restrict__ q, const float* __restrict__ k,
    const float* __restrict__ v,
    const float* __restrict__ coef_q, const float* __restrict__ coef_k,
    const float* __restrict__ mask_normer,
    const unsigned short* __restrict__ wsKV, float* __restrict__ out) {
  const int ch = blockIdx.x, h = blockIdx.y, t = threadIdx.x;
  __shared__ alignas(16) short qb[C * PITCH];    // q_bar  [i][a]
  __shared__ alignas(16) short kbs[C * PITCH];   // k_bar [j][a]; later S0 [c][a]
  __shared__ alignas(16) short vT[C * PITCH];    // v^T    [c][j]
  __shared__ alignas(16) short Ab[C * PITCH];    // A      [i][j]
  __shared__ float ssp[C][2];                    // rms partials per row

  const size_t base = (size_t)(h * S + ch * C) * D;
  const float* qp = q + base;
  const float* kp = k + base;
  const float* vp = v + base;
  const float* cq = coef_q + h * S + ch * C;
  const float* ck = coef_k + h * S + ch * C;
  const float* mn = mask_normer + h * S + ch * C;

  // ---- S0 in-block prefix: thread owns 8 elems (row t>>3, cols (t&7)*8..)
  float acc8[8] = {0.f, 0.f, 0.f, 0.f, 0.f, 0.f, 0.f, 0.f};
  {
    const unsigned short* sp = wsKV + (size_t)h * NC * DD + 8 * t;
#pragma unroll 4
    for (int c = 0; c < ch; ++c) {
      uint4v xx = *reinterpret_cast<const uint4v*>(sp + (size_t)c * DD);
#pragma unroll
      for (int u = 0; u < 4; ++u) {
        acc8[2 * u]     += bf16_to_f(xx[u] & 0xffffu);
        acc8[2 * u + 1] += bf16_to_f(xx[u] >> 16);
      }
    }
  }

  // ---- staging rows: thread t -> row i = t>>3, 8 cols c0 = (t&7)*8
  {
    const int i = t >> 3, c0 = (t & 7) * 8;
    const float sq = cq[i] / mn[i];
    const float sk = ck[i];
    bf16x8 wq, wk;
#pragma unroll
    for (int u0 = 0; u0 < 8; u0 += 4) {
      F4 qv = *reinterpret_cast<const F4*>(qp + i * D + c0 + u0);
      F4 kv = *reinterpret_cast<const F4*>(kp + i * D + c0 + u0);
#pragma unroll
      for (int u = 0; u < 4; ++u) {
        wq[u0 + u] = (short)rne_bf16(qv.v[u] * sq);
        wk[u0 + u] = (short)rne_bf16(kv.v[u] * sk);
      }
    }
    *reinterpret_cast<bf16x8*>(&qb[i * PITCH + c0]) = wq;
    *reinterpret_cast<bf16x8*>(&kbs[i * PITCH + c0]) = wk;
  }
  // ---- vT staging: col = t&63, rows i0 = 8*(t>>6)
  {
    const int col = t & 63, i0 = 8 * (t >> 6);
    unsigned pr[4];
#pragma unroll
    for (int u2 = 0; u2 < 4; ++u2) {
      float x0 = vp[(size_t)(i0 + 2 * u2) * D + col];
      float x1 = vp[(size_t)(i0 + 2 * u2 + 1) * D + col];
      pr[u2] = (unsigned)rne_bf16(x0) | ((unsigned)rne_bf16(x1) << 16);
    }
    uint4v wv = {pr[0], pr[1], pr[2], pr[3]};
    *reinterpret_cast<uint4v*>(&vT[col * PITCH + i0]) = wv;
  }
  __syncthreads();

  const int lane = t & 63, w = t >> 6;
  const int arow = lane & 15, kg = lane >> 4;
  const int m = w >> 1, n0 = 2 * (w & 1);
  const int rbase = (16 * m + arow) * PITCH + 8 * kg;

  bf16x8 qa0 = *reinterpret_cast<const bf16x8*>(&qb[rbase]);
  bf16x8 qa1 = *reinterpret_cast<const bf16x8*>(&qb[rbase + 32]);

  // ---- A-stage: wave computes rows 16m..16m+15, cols 16n0..16n0+31
#pragma unroll
  for (int nn = 0; nn < 2; ++nn) {
    const int n = n0 + nn;
    const int bb = (16 * n + arow) * PITCH + 8 * kg;
    bf16x8 b0 = *reinterpret_cast<const bf16x8*>(&kbs[bb]);
    bf16x8 b1 = *reinterpret_cast<const bf16x8*>(&kbs[bb + 32]);
    f32x4 z = {0.f, 0.f, 0.f, 0.f};
    z = __builtin_amdgcn_mfma_f32_16x16x32_bf16(qa0, b0, z, 0, 0, 0);
    z = __builtin_amdgcn_mfma_f32_16x16x32_bf16(qa1, b1, z, 0, 0, 0);
#pragma unroll
    for (int r = 0; r < 4; ++r) {
      int i = 16 * m + 4 * kg + r;
      int j = 16 * n + arow;
      float x = (j <= i) ? z[r] : 0.f;
      Ab[i * PITCH + j] = (short)rne_bf16(x);
    }
  }
  __syncthreads();   // Ab complete; all kbs(k_bar) reads done

  // ---- O partial = A*V; meanwhile publish S0 tile into kbs (k_bar is dead)
  bf16x8 aa0 = *reinterpret_cast<const bf16x8*>(&Ab[rbase]);
  bf16x8 aa1 = *reinterpret_cast<const bf16x8*>(&Ab[rbase + 32]);
  {
    bf16x8 ws0;
#pragma unroll
    for (int u = 0; u < 8; ++u) ws0[u] = (short)rne_bf16(acc8[u]);
    *reinterpret_cast<bf16x8*>(&kbs[(t >> 3) * PITCH + (t & 7) * 8]) = ws0;
  }
  f32x4 accO[2];
#pragma unroll
  for (int nn = 0; nn < 2; ++nn) {
    const int n = n0 + nn;
    const int bb = (16 * n + arow) * PITCH + 8 * kg;
    bf16x8 v0 = *reinterpret_cast<const bf16x8*>(&vT[bb]);
    bf16x8 v1 = *reinterpret_cast<const bf16x8*>(&vT[bb + 32]);
    f32x4 z = {0.f, 0.f, 0.f, 0.f};
    z = __builtin_amdgcn_mfma_f32_16x16x32_bf16(aa0, v0, z, 0, 0, 0);
    z = __builtin_amdgcn_mfma_f32_16x16x32_bf16(aa1, v1, z, 0, 0, 0);
    accO[nn] = z;
  }
  __syncthreads();   // S0 tile visible

  // ---- O += q_bar * S0 (B-fragments from LDS)
#pragma unroll
  for (int nn = 0; nn < 2; ++nn) {
    const int n = n0 + nn;
    const int bb = (16 * n + arow) * PITCH + 8 * kg;
    bf16x8 h0 = *reinterpret_cast<const bf16x8*>(&kbs[bb]);
    bf16x8 h1 = *reinterpret_cast<const bf16x8*>(&kbs[bb + 32]);
    accO[nn] = __builtin_amdgcn_mfma_f32_16x16x32_bf16(qa0, h0, accO[nn], 0, 0, 0);
    accO[nn] = __builtin_amdgcn_mfma_f32_16x16x32_bf16(qa1, h1, accO[nn], 0, 0, 0);
  }

  // ---- rms partial: reduce over this wave's 32 cols, exchange halves
#pragma unroll
  for (int r = 0; r < 4; ++r) {
    float ss = accO[0][r] * accO[0][r] + accO[1][r] * accO[1][r];
#pragma unroll
    for (int off = 1; off < 16; off <<= 1) ss += __shfl_xor(ss, off);
    if (arow == 0) ssp[16 * m + 4 * kg + r][w & 1] = ss;
  }
  __syncthreads();

  // ---- epilogue: scale + store
  float* op = out + base;
#pragma unroll
  for (int r = 0; r < 4; ++r) {
    const int i = 16 * m + 4 * kg + r;
    const float tot = ssp[i][0] + ssp[i][1];
    const float sc = rsqrtf(tot * (1.0f / D) + 1e-6f);
#pragma unroll
    for (int nn = 0; nn < 2; ++nn)
      op[(size_t)i * D + 16 * (n0 + nn) + arow] = accO[nn][r] * sc;
  }
}

// ---------------------------------------------------------------------------
extern "C" void kernel_launch(void* const* d_in, const int* in_sizes, int n_in,
                              void* d_out, int out_size, void* d_ws, size_t ws_size,
                              hipStream_t stream) {
  (void)in_sizes; (void)n_in; (void)out_size; (void)ws_size;
  const float* q  = (const float*)d_in[0];
  const float* k  = (const float*)d_in[1];
  const float* v  = (const float*)d_in[2];
  const float* cq = (const float*)d_in[3];
  const float* ck = (const float*)d_in[4];
  const float* mn = (const float*)d_in[5];
  float* out = (float*)d_out;

  unsigned short* wsKV = (unsigned short*)d_ws;   // H*NC*D*D bf16 (4 MiB)

  k_chunk_sums<<<dim3(NC, H), dim3(512), 0, stream>>>(k, v, ck, wsKV);
  k_chunk_out<<<dim3(NC, H), dim3(512), 0, stream>>>(q, k, v, cq, ck, mn, wsKV, out);
}

// Round 12
// 26.047 us; speedup vs baseline: 1.0732x; 1.0732x over previous
//
#include <hip/hip_runtime.h>

// Problem constants (B=1)
#define H 8
#define S 4096
#define D 64          // D1 == D2 == 64
#define C 64          // producer chunk length
#define NC (S / C)    // 64 chunk states per head
#define DD (D * D)
#define C2 128        // consumer chunk length
#define NC2 (S / C2)  // 32 consumer chunks per head
#define PITCH 72      // bf16 LDS pitch for 64-wide rows (144B, 4-bank rotation)
#define PITCH2 136    // bf16 LDS pitch for 128-wide rows (272B, 4-bank rotation)

typedef short bf16x8 __attribute__((ext_vector_type(8)));
typedef float f32x4 __attribute__((ext_vector_type(4)));
typedef unsigned uint4v __attribute__((ext_vector_type(4)));

struct alignas(16) F4 { float v[4]; };

__device__ inline unsigned short rne_bf16(float x) {
  unsigned u = __builtin_bit_cast(unsigned, x);
  unsigned r = u + 0x7fffu + ((u >> 16) & 1u);
  return (unsigned short)(r >> 16);
}
__device__ inline float bf16_to_f(unsigned hw) {
  return __builtin_bit_cast(float, hw << 16);
}

// ---------------------------------------------------------------------------
// Kernel 1 (512 thr, 8 waves): per-chunk state via MFMA, bf16 out:
//   wsKV[h][ch][c][a] = bf16( sum_i v[i][c] * k_bar[i][a] ),  ch over C=64
// ---------------------------------------------------------------------------
__global__ __launch_bounds__(512, 4) void k_chunk_sums(
    const float* __restrict__ k, const float* __restrict__ v,
    const float* __restrict__ coef_k, unsigned short* __restrict__ wsKV) {
  const int ch = blockIdx.x, h = blockIdx.y, t = threadIdx.x;
  __shared__ alignas(16) short kT[C * PITCH];   // k_bar^T [a][i]
  __shared__ alignas(16) short vT[C * PITCH];   // v^T     [c][i]

  const float* kp = k + (size_t)(h * S + ch * C) * D;
  const float* vp = v + (size_t)(h * S + ch * C) * D;
  const float* ck = coef_k + h * S + ch * C;

  {
    const int col = t & 63, grp = t >> 6;
    const bool isK = grp < 4;
    const int i0 = (grp & 3) * 16;
    const float* src = isK ? kp : vp;
    short* dstT = isK ? kT : vT;
    unsigned pr[8];
#pragma unroll
    for (int u2 = 0; u2 < 8; ++u2) {
      const int ia = i0 + 2 * u2, ib = ia + 1;
      float x0 = src[ia * D + col];
      float x1 = src[ib * D + col];
      if (isK) { x0 *= ck[ia]; x1 *= ck[ib]; }
      pr[u2] = (unsigned)rne_bf16(x0) | ((unsigned)rne_bf16(x1) << 16);
    }
#pragma unroll
    for (int g = 0; g < 2; ++g) {
      uint4v wv = {pr[4 * g], pr[4 * g + 1], pr[4 * g + 2], pr[4 * g + 3]};
      *reinterpret_cast<uint4v*>(&dstT[col * PITCH + i0 + 8 * g]) = wv;
    }
  }
  __syncthreads();

  const int lane = t & 63, w = t >> 6;
  const int arow = lane & 15, kg = lane >> 4;
  const int m = w >> 1, n0 = 2 * (w & 1);
  const int abase = (16 * m + arow) * PITCH + 8 * kg;
  bf16x8 a0 = *reinterpret_cast<const bf16x8*>(&vT[abase]);
  bf16x8 a1 = *reinterpret_cast<const bf16x8*>(&vT[abase + 32]);
  unsigned short* dst = wsKV + (size_t)(h * NC + ch) * DD;
#pragma unroll
  for (int nn = 0; nn < 2; ++nn) {
    const int n = n0 + nn;
    const int bb = (16 * n + arow) * PITCH + 8 * kg;
    bf16x8 b0 = *reinterpret_cast<const bf16x8*>(&kT[bb]);
    bf16x8 b1 = *reinterpret_cast<const bf16x8*>(&kT[bb + 32]);
    f32x4 z = {0.f, 0.f, 0.f, 0.f};
    z = __builtin_amdgcn_mfma_f32_16x16x32_bf16(a0, b0, z, 0, 0, 0);
    z = __builtin_amdgcn_mfma_f32_16x16x32_bf16(a1, b1, z, 0, 0, 0);
#pragma unroll
    for (int r = 0; r < 4; ++r)
      dst[(16 * m + 4 * kg + r) * D + 16 * n + arow] = rne_bf16(z[r]);
  }
}

// ---------------------------------------------------------------------------
// Kernel 2: exclusive prefix scan across the 64 chunk states (per head),
// bf16 in/out, f32 running sum, 32-deep load batching.
// ---------------------------------------------------------------------------
__global__ __launch_bounds__(64) void k_scan(unsigned* __restrict__ wsKV) {
  const int seg = blockIdx.x, h = blockIdx.y, t = threadIdx.x;
  const int e0 = seg * 64 + t;               // dword index within 2048-dword matrix
  float run0 = 0.f, run1 = 0.f;
  for (int base = 0; base < NC; base += 32) {
    unsigned x[32];
#pragma unroll
    for (int u = 0; u < 32; ++u)
      x[u] = wsKV[(size_t)(h * NC + base + u) * 2048 + e0];
#pragma unroll
    for (int u = 0; u < 32; ++u) {
      wsKV[(size_t)(h * NC + base + u) * 2048 + e0] =
          (unsigned)rne_bf16(run0) | ((unsigned)rne_bf16(run1) << 16);
      run0 += bf16_to_f(x[u] & 0xffffu);
      run1 += bf16_to_f(x[u] >> 16);
    }
  }
}

// ---------------------------------------------------------------------------
// Kernel 3 (1024 thr, 16 waves, 1 block/CU): C2=128 output chunk.
//   A = tril(q_bar K_bar^T) (128x128);  O = q_bar*S0 + A*V;  rmsnorm(O).
// S0 = scan output at chunk-state index 2*ch2 (exact same values as before).
// S0 fragments hoisted to entry (latency hidden under staging + A-stage).
// ---------------------------------------------------------------------------
__global__ __launch_bounds__(1024, 4) void k_chunk_out(
    const float* __restrict__ q, const float* __restrict__ k,
    const float* __restrict__ v,
    const float* __restrict__ coef_q, const float* __restrict__ coef_k,
    const float* __restrict__ mask_normer,
    const unsigned short* __restrict__ wsKV, float* __restrict__ out) {
  const int ch2 = blockIdx.x, h = blockIdx.y, t = threadIdx.x;
  __shared__ alignas(16) short qb[C2 * PITCH];    // q_bar [i][a]   (128 x 64)
  __shared__ alignas(16) short kb[C2 * PITCH];    // k_bar [j][a]   (128 x 64)
  __shared__ alignas(16) short vT[D * PITCH2];    // v^T   [c][j]   (64 x 128)
  __shared__ alignas(16) short Ab[C2 * PITCH2];   // A     [i][j]   (128 x 128)
  __shared__ float ssp[C2][2];

  const size_t base = (size_t)(h * S + ch2 * C2) * D;
  const float* qp = q + base;
  const float* kp = k + base;
  const float* vp = v + base;
  const float* cq = coef_q + h * S + ch2 * C2;
  const float* ck = coef_k + h * S + ch2 * C2;
  const float* mn = mask_normer + h * S + ch2 * C2;

  const int lane = t & 63, w = t >> 6;         // w in 0..15
  const int arow = lane & 15, kg = lane >> 4;
  const int m = w >> 1;                        // row-tile 0..7
  const int half = w & 1;

  // ---- hoisted S0 fragment loads (O-stage B-operand), issue FIRST ----
  const unsigned short* s0p = wsKV + (size_t)(h * NC + 2 * ch2) * DD;
  bf16x8 s0f[2][2];
#pragma unroll
  for (int nn = 0; nn < 2; ++nn) {
    const int n = 2 * half + nn;               // c-tile 0..3
    const int gb = (16 * n + arow) * D + 8 * kg;
    s0f[nn][0] = *reinterpret_cast<const bf16x8*>(s0p + gb);
    s0f[nn][1] = *reinterpret_cast<const bf16x8*>(s0p + gb + 32);
  }

  // ---- staging rows: thread t -> row i = t>>3 (0..127), 8 cols (t&7)*8 ----
  {
    const int i = t >> 3, c0 = (t & 7) * 8;
    const float sq = cq[i] / mn[i];
    const float sk = ck[i];
    bf16x8 wq, wk;
#pragma unroll
    for (int u0 = 0; u0 < 8; u0 += 4) {
      F4 qv = *reinterpret_cast<const F4*>(qp + i * D + c0 + u0);
      F4 kv = *reinterpret_cast<const F4*>(kp + i * D + c0 + u0);
#pragma unroll
      for (int u = 0; u < 4; ++u) {
        wq[u0 + u] = (short)rne_bf16(qv.v[u] * sq);
        wk[u0 + u] = (short)rne_bf16(kv.v[u] * sk);
      }
    }
    *reinterpret_cast<bf16x8*>(&qb[i * PITCH + c0]) = wq;
    *reinterpret_cast<bf16x8*>(&kb[i * PITCH + c0]) = wk;
  }
  // ---- vT staging: col = t&63, rows i0 = 8*(t>>6) (0..127) ----
  {
    const int col = t & 63, i0 = 8 * (t >> 6);
    unsigned pr[4];
#pragma unroll
    for (int u2 = 0; u2 < 4; ++u2) {
      float x0 = vp[(size_t)(i0 + 2 * u2) * D + col];
      float x1 = vp[(size_t)(i0 + 2 * u2 + 1) * D + col];
      pr[u2] = (unsigned)rne_bf16(x0) | ((unsigned)rne_bf16(x1) << 16);
    }
    uint4v wv = {pr[0], pr[1], pr[2], pr[3]};
    *reinterpret_cast<uint4v*>(&vT[col * PITCH2 + i0]) = wv;
  }
  __syncthreads();

  // q A-fragments for row-tile m (reused by A-stage and S0 MFMAs)
  const int qbase = (16 * m + arow) * PITCH + 8 * kg;
  bf16x8 qa0 = *reinterpret_cast<const bf16x8*>(&qb[qbase]);
  bf16x8 qa1 = *reinterpret_cast<const bf16x8*>(&qb[qbase + 32]);

  // ---- A-stage: wave w -> row-tile m, col-tiles 4*half .. 4*half+3 ----
#pragma unroll
  for (int nn = 0; nn < 4; ++nn) {
    const int n = 4 * half + nn;
    const int bb = (16 * n + arow) * PITCH + 8 * kg;
    bf16x8 b0 = *reinterpret_cast<const bf16x8*>(&kb[bb]);
    bf16x8 b1 = *reinterpret_cast<const bf16x8*>(&kb[bb + 32]);
    f32x4 z = {0.f, 0.f, 0.f, 0.f};
    z = __builtin_amdgcn_mfma_f32_16x16x32_bf16(qa0, b0, z, 0, 0, 0);
    z = __builtin_amdgcn_mfma_f32_16x16x32_bf16(qa1, b1, z, 0, 0, 0);
#pragma unroll
    for (int r = 0; r < 4; ++r) {
      int i = 16 * m + 4 * kg + r;
      int j = 16 * n + arow;
      float x = (j <= i) ? z[r] : 0.f;
      Ab[i * PITCH2 + j] = (short)rne_bf16(x);
    }
  }
  __syncthreads();   // Ab complete (each row-tile written by 2 waves)

  // ---- O-stage: wave w -> row-tile m, out c-tiles 2*half .. 2*half+1 ----
  // A-operand fragments of Ab row-tile m over K=128 (4 frags)
  const int abase2 = (16 * m + arow) * PITCH2 + 8 * kg;
  bf16x8 aa[4];
#pragma unroll
  for (int f = 0; f < 4; ++f)
    aa[f] = *reinterpret_cast<const bf16x8*>(&Ab[abase2 + 32 * f]);

  f32x4 accO[2];
#pragma unroll
  for (int nn = 0; nn < 2; ++nn) {
    const int n = 2 * half + nn;
    const int vb = (16 * n + arow) * PITCH2 + 8 * kg;
    f32x4 z = {0.f, 0.f, 0.f, 0.f};
#pragma unroll
    for (int f = 0; f < 4; ++f) {
      bf16x8 vf = *reinterpret_cast<const bf16x8*>(&vT[vb + 32 * f]);
      z = __builtin_amdgcn_mfma_f32_16x16x32_bf16(aa[f], vf, z, 0, 0, 0);
    }
    z = __builtin_amdgcn_mfma_f32_16x16x32_bf16(qa0, s0f[nn][0], z, 0, 0, 0);
    z = __builtin_amdgcn_mfma_f32_16x16x32_bf16(qa1, s0f[nn][1], z, 0, 0, 0);
    accO[nn] = z;
  }

  // ---- rms partials: this wave covers 32 of 64 cols for its rows ----
#pragma unroll
  for (int r = 0; r < 4; ++r) {
    float ss = accO[0][r] * accO[0][r] + accO[1][r] * accO[1][r];
#pragma unroll
    for (int off = 1; off < 16; off <<= 1) ss += __shfl_xor(ss, off);
    if (arow == 0) ssp[16 * m + 4 * kg + r][half] = ss;
  }
  __syncthreads();

  // ---- epilogue: scale + store ----
  float* op = out + base;
#pragma unroll
  for (int r = 0; r < 4; ++r) {
    const int i = 16 * m + 4 * kg + r;
    const float tot = ssp[i][0] + ssp[i][1];
    const float sc = rsqrtf(tot * (1.0f / D) + 1e-6f);
#pragma unroll
    for (int nn = 0; nn < 2; ++nn)
      op[(size_t)i * D + 16 * (2 * half + nn) + arow] = accO[nn][r] * sc;
  }
}

// ---------------------------------------------------------------------------
extern "C" void kernel_launch(void* const* d_in, const int* in_sizes, int n_in,
                              void* d_out, int out_size, void* d_ws, size_t ws_size,
                              hipStream_t stream) {
  (void)in_sizes; (void)n_in; (void)out_size; (void)ws_size;
  const float* q  = (const float*)d_in[0];
  const float* k  = (const float*)d_in[1];
  const float* v  = (const float*)d_in[2];
  const float* cq = (const float*)d_in[3];
  const float* ck = (const float*)d_in[4];
  const float* mn = (const float*)d_in[5];
  float* out = (float*)d_out;

  unsigned short* wsKV = (unsigned short*)d_ws;   // H*NC*D*D bf16 (4 MiB)

  k_chunk_sums<<<dim3(NC, H), dim3(512), 0, stream>>>(k, v, ck, wsKV);
  k_scan<<<dim3(32, H), dim3(64), 0, stream>>>((unsigned*)d_ws);
  k_chunk_out<<<dim3(NC2, H), dim3(1024), 0, stream>>>(q, k, v, cq, ck, mn, wsKV, out);
}